// Round 8
// baseline (807.785 us; speedup 1.0000x reference)
//
#include <hip/hip_runtime.h>

#define S_LEN 4096
#define NBATCH 2
#define ROWS (NBATCH*S_LEN)          // 8192
#define OUT_ELEMS 2097152            // B*2*S*H
#define NBLK 512                     // persistent grid: 2 blocks/CU on 256 CUs

typedef _Float16 f16;
typedef _Float16 f16x8 __attribute__((ext_vector_type(8)));
typedef _Float16 f16x4 __attribute__((ext_vector_type(4)));
typedef float f32x4 __attribute__((ext_vector_type(4)));

// ---- workspace layout (bytes) ----
#define MT_OFF    0x000000   // 4 x 256x256 f16
#define BIAS_OFF  0x080000   // 4 x 256 f32
#define SC_OFF    0x081000   // scalars: kc, nf2
#define BAR_OFF   0x082000   // barrier state: [count, generation]
#define QH_OFF    0x100000   // 8192x256 f16   4 MB
#define KH_OFF    0x500000   // 8192x256 f16   4 MB
#define VT_OFF    0x900000   // [b][256][4096] f16  4 MB
#define Q2P_OFF   0xD00000   // 4 x 8192 f32 partials
#define K2P_OFF   0xD20000   // 4 x 8192 f32 partials
#define LS_OFF    0xD40000   // 8192 f32
#define RS_OFF    0xE00000   // rsum[b][32sb][32tb][2][128] f32   2 MB
#define ESTP_OFF  0x1200000  // 4 splitk chunks x 8192x256 f32   32 MB (zeroed)
#define PW_OFF    0x3200000  // [b][4096][4096] f16 unnormalized P   64 MB
#define WS_NEED   0x7200000  // 114 MB

#define MFMA16(A,B,C) __builtin_amdgcn_mfma_f32_16x16x32_f16(A,B,C,0,0,0)

__device__ __forceinline__ void async_cp16(f16* lds, const f16* g) {
  __builtin_amdgcn_global_load_lds(
      (const __attribute__((address_space(1))) void*)g,
      (__attribute__((address_space(3))) void*)lds, 16, 0, 0);
}

// LDS tiles [TR][32] f16 with chunk-XOR swizzle.
template<int TR>
__device__ __forceinline__ void stage16(f16* lds, const f16* g, int stride, int tid) {
#pragma unroll
  for (int i = 0; i < TR/64; ++i) {
    int idx = i*256 + tid;
    int row = idx >> 2;
    int c = (idx & 3) ^ ((row >> 1) & 3);
    async_cp16(lds + idx*8, g + (size_t)row*stride + c*8);
  }
}

template<int TR>
__device__ __forceinline__ void stage32(f16* lds, const float* g, int stride, int tid) {
#pragma unroll
  for (int i = 0; i < TR/32; ++i) {
    int idx = i*256 + tid;
    int row = idx >> 3, c = idx & 7;
    const float4* gp = (const float4*)(g + (size_t)row*stride + c*4);
    float4 v = *gp;
    f16x4 h; h[0]=(f16)v.x; h[1]=(f16)v.y; h[2]=(f16)v.z; h[3]=(f16)v.w;
    int slot = (((c >> 1) ^ ((row >> 1) & 3)) << 3) + (c & 1)*4;
    *(f16x4*)(lds + row*32 + slot) = h;
  }
}

template<int MI, int NJ>
__device__ __forceinline__ void mfma_step(const f16* Asm, const f16* Bsm, int lane,
                                          int wm, int wn, f32x4 (&acc)[MI][NJ]) {
  f16x8 a[MI], b[NJ];
  int rr = lane & 15, kc = lane >> 4;
#pragma unroll
  for (int i=0;i<MI;i++) {
    int m = wm + i*16 + rr;
    a[i] = *(const f16x8*)(Asm + m*32 + ((kc ^ ((m>>1)&3)) << 3));
  }
#pragma unroll
  for (int j=0;j<NJ;j++) {
    int n = wn + j*16 + rr;
    b[j] = *(const f16x8*)(Bsm + n*32 + ((kc ^ ((n>>1)&3)) << 3));
  }
#pragma unroll
  for (int i=0;i<MI;i++)
#pragma unroll
    for (int j=0;j<NJ;j++) acc[i][j] = MFMA16(a[i], b[j], acc[i][j]);
}

// ---- software grid barrier (sense-reversal; all NBLK blocks co-resident) ----
__device__ __forceinline__ void gbar(int* bar) {
  __syncthreads();
  if (threadIdx.x == 0) {
    __threadfence();   // flush XCD L2 (release)
    int gen = __hip_atomic_load(&bar[1], __ATOMIC_RELAXED, __HIP_MEMORY_SCOPE_AGENT);
    int old = __hip_atomic_fetch_add(&bar[0], 1, __ATOMIC_ACQ_REL, __HIP_MEMORY_SCOPE_AGENT);
    if (old == NBLK-1) {
      __hip_atomic_store(&bar[0], 0, __ATOMIC_RELAXED, __HIP_MEMORY_SCOPE_AGENT);
      __hip_atomic_fetch_add(&bar[1], 1, __ATOMIC_RELEASE, __HIP_MEMORY_SCOPE_AGENT);
    } else {
      while (__hip_atomic_load(&bar[1], __ATOMIC_ACQUIRE, __HIP_MEMORY_SCOPE_AGENT) == gen)
        __builtin_amdgcn_s_sleep(2);
    }
    __threadfence();   // invalidate stale caches (acquire)
  }
  __syncthreads();
}

// ---- init: build Mt/bias, scalars, zero estp + barrier ----
__global__ __launch_bounds__(256)
void k_init(const float* Wqr, const float* Wqi, const float* bqr, const float* bqi,
            const float* Wkr, const float* Wki, const float* bkr, const float* bki,
            const float* Wvr, const float* Wvi, const float* bvr, const float* bvi,
            const float* Wpr, const float* Wpi, const float* bpr, const float* bpi,
            f16* Mt, float* bias, float* sc, float* estp, int* bar,
            const float* nf, const float* tau) {
  int idx = blockIdx.x*256 + threadIdx.x;    // 0..524287
  if (idx < 262144) {
    int mat = idx >> 16, rest = idx & 65535;
    int n = rest >> 8, k = rest & 255;
    const float *Wr, *Wi, *br, *bi;
    if (mat == 0)      { Wr=Wqr; Wi=Wqi; br=bqr; bi=bqi; }
    else if (mat == 1) { Wr=Wkr; Wi=Wki; br=bkr; bi=bki; }
    else if (mat == 2) { Wr=Wvr; Wi=Wvi; br=bvr; bi=bvi; }
    else               { Wr=Wpr; Wi=Wpi; br=bpr; bi=bpi; }
    int d = k & 127, h = n & 127;
    float w = (k < 128) ? ((n < 128) ? Wr[h*128+d] : Wi[h*128+d])
                        : ((n < 128) ? -Wi[h*128+d] : Wr[h*128+d]);
    Mt[mat*65536 + n*256 + k] = (f16)w;
    if (k == 0)
      bias[mat*256 + n] = (n < 128) ? (br[n] - bi[n]) : (br[n-128] + bi[n-128]);
  }
  float4 z = make_float4(0.f,0.f,0.f,0.f);
#pragma unroll
  for (int u = 0; u < 4; ++u)
    ((float4*)estp)[idx + u*524288] = z;     // 32 MB
  if (idx == 0) {
    float t = tau[0];
    float c = __builtin_log2f(1.0f + __builtin_exp2f(t * 1.4426950408889634f))
              * 0.6931471805599453f;
    sc[0] = -c * 0.08838834764831845f;       // kc = -softplus(tau)/sqrt(128)
    sc[1] = nf[0]*nf[0] + 1e-6f;             // nf^2 + EPS
    bar[0] = 0; bar[1] = 0;
  }
}

// ================== persistent mega-kernel: 4 phases, 3 grid barriers =======
__global__ __launch_bounds__(256, 2)
void k_mega(const float* Zq, const float* Zk, const float* Zv,
            const f16* Mt, const float* bias, const float* sc,
            f16* Qh, f16* Kh, f16* Vt, float* q2p, float* k2p,
            float* rsum, float* lsum, float* estp, f16* Pws,
            float* attn, float* outp, int* bar) {
  __shared__ __align__(16) char smem[18496];
  int bid = blockIdx.x, tid = threadIdx.x;
  int lane = tid & 63, w = tid >> 6;
  int rr = (lane>>4)*4, cc = lane & 15;

  // ---------------- phase 0: projections (768 jobs) ----------------
  for (int job = bid; job < 768; job += NBLK) {
    f16* Asm = (f16*)smem;                  // 64x32
    f16* Bsm = (f16*)(smem + 4096);         // 128x32
    float* bias_s = (float*)(smem + 12288); // 128
    int mode = job >> 8, rem = job & 255;
    int m0 = (rem >> 1)*64, n0 = (rem & 1)*128;
    const float* Z = (mode==0) ? Zq : (mode==1 ? Zk : Zv);
    const f16* Bt = Mt + mode*65536;
    if (tid < 128) bias_s[tid] = bias[mode*256 + n0 + tid];
    int b = m0 >> 12, s0 = m0 & 4095;
    int wm = (w >> 1)*32, wn = (w & 1)*64;
    f32x4 acc[2][4] = {};
    for (int kb = 0; kb < 8; ++kb) {
      int k0 = kb*32;
      int part = k0 >> 7, d0 = k0 & 127;
      const float* Ag = Z + (((size_t)(b*2 + part))*S_LEN + s0)*128 + d0;
      stage32<64>(Asm, Ag, 128, tid);
      stage16<128>(Bsm, Bt + n0*256 + k0, 256, tid);
      __syncthreads();
      mfma_step<2,4>(Asm, Bsm, lane, wm, wn, acc);
      __syncthreads();
    }
    if (mode < 2) {
      f16* O = (mode==0) ? Qh : Kh;
      float rs[2][4];
#pragma unroll
      for (int i=0;i<2;i++)
#pragma unroll
        for (int r=0;r<4;r++) rs[i][r]=0.f;
#pragma unroll
      for (int i=0;i<2;i++)
#pragma unroll
        for (int j=0;j<4;j++) {
          int cl = wn + j*16 + cc;
          float bv = bias_s[cl];
#pragma unroll
          for (int r=0;r<4;r++) {
            int rg = m0 + wm + i*16 + rr + r;
            f16 hv = (f16)(acc[i][j][r] + bv);
            O[(size_t)rg*256 + n0 + cl] = hv;
            float fv = (float)hv;
            rs[i][r] += fv*fv;
          }
        }
#pragma unroll
      for (int m=8;m>=1;m>>=1)
#pragma unroll
        for (int i=0;i<2;i++)
#pragma unroll
          for (int r=0;r<4;r++) rs[i][r] += __shfl_xor(rs[i][r], m, 64);
      if (cc == 0) {
        float* T = ((mode==0) ? q2p : k2p) + ((n0>>7)*2 + (wn>>6))*8192;
#pragma unroll
        for (int i=0;i<2;i++)
#pragma unroll
          for (int r=0;r<4;r++)
            T[m0 + wm + i*16 + rr + r] = rs[i][r];   // direct partial store
      }
    } else {
#pragma unroll
      for (int i=0;i<2;i++) {
        int t0 = s0 + wm + i*16 + rr;
#pragma unroll
        for (int j=0;j<4;j++) {
          int cl = wn + j*16 + cc;
          float bv = bias_s[cl];
          f16x4 h4;
#pragma unroll
          for (int r=0;r<4;r++) h4[r] = (f16)(acc[i][j][r] + bv);
          *(f16x4*)(Vt + (size_t)b*1048576 + (size_t)(n0+cl)*4096 + t0) = h4;
        }
      }
    }
    __syncthreads();
  }
  gbar(bar);

  // ---------------- phase 1: QK lower tiles (1056 jobs) ----------------
  for (int job = bid; job < 1056; job += NBLK) {
    f16* Asm = (f16*)smem;                   // 128x32
    f16* Bsm = (f16*)(smem + 8192);          // 128x32
    float* q2s = (float*)(smem + 16384);
    float* k2s = (float*)(smem + 16896);
    int b = job / 528, r = job % 528;
    int sb = (int)((__builtin_sqrtf(8.f*(float)r + 1.f) - 1.f)*0.5f);
    while ((sb+1)*(sb+2)/2 <= r) sb++;
    while (sb*(sb+1)/2 > r) sb--;
    int tb = r - sb*(sb+1)/2;
    int s0 = sb*128, t0 = tb*128;
    if (tid < 128) {
      int rq = b*S_LEN + s0 + tid, rk = b*S_LEN + t0 + tid;
      q2s[tid] = q2p[rq] + q2p[8192+rq] + q2p[16384+rq] + q2p[24576+rq];
      k2s[tid] = k2p[rk] + k2p[8192+rk] + k2p[16384+rk] + k2p[24576+rk];
    }
    float kcs = sc[0], nf2 = sc[1];
    int wm = (w >> 1)*64, wn = (w & 1)*64;
    const f16* Ag = Qh + ((size_t)(b*S_LEN) + s0)*256;
    const f16* Bg = Kh + ((size_t)(b*S_LEN) + t0)*256;
    f32x4 acc[4][4] = {};
    for (int kb=0;kb<8;kb++) {
      stage16<128>(Asm, Ag + kb*32, 256, tid);
      stage16<128>(Bsm, Bg + kb*32, 256, tid);
      __syncthreads();
      mfma_step<4,4>(Asm, Bsm, lane, wm, wn, acc);
      __syncthreads();
    }
    bool diag = (tb == sb);
    float rs[4][4];
#pragma unroll
    for (int i=0;i<4;i++)
#pragma unroll
      for (int rg=0;rg<4;rg++) rs[i][rg]=0.f;
#pragma unroll
    for (int i=0;i<4;i++)
#pragma unroll
      for (int j=0;j<4;j++) {
        int cl = wn + j*16 + cc;
        float kv = k2s[cl];
#pragma unroll
        for (int rg=0;rg<4;rg++) {
          int rl = wm + i*16 + rr + rg;
          float xx = nf2 + q2s[rl] + kv - 2.0f*acc[i][j][rg];
          float P = __builtin_exp2f(kcs * __builtin_log2f(__builtin_fmaxf(xx, 1e-6f)));
          if (diag && (t0+cl) > (s0+rl)) P = 0.f;
          Pws[((size_t)(b*S_LEN) + s0 + rl)*S_LEN + t0 + cl] = (f16)P;
          rs[i][rg] += P;
        }
      }
#pragma unroll
    for (int m=8;m>=1;m>>=1)
#pragma unroll
      for (int i=0;i<4;i++)
#pragma unroll
        for (int rg=0;rg<4;rg++) rs[i][rg] += __shfl_xor(rs[i][rg], m, 64);
    if (cc == 0) {
      float* R = rsum + ((size_t)((b*32+sb)*32+tb))*256 + (wn>>6)*128;
#pragma unroll
      for (int i=0;i<4;i++)
#pragma unroll
        for (int rg=0;rg<4;rg++)
          R[wm + i*16 + rr + rg] = rs[i][rg];
    }
    __syncthreads();
  }
  gbar(bar);

  // ---------------- phase 2: PV (256 jobs) || norm+lsum (256 blocks) -------
  if (bid < 256) {
    // triangle-paired split-K PV: pair p=(rows p, 31-p) => 33 K-tiles constant
    f16* Asm = (f16*)smem;
    f16* Bsm = (f16*)(smem + 8192);
    int j = bid;
    int p = j & 15, spl = (j>>4)&3, nbh = (j>>6)&1, b = j>>7;
    int h0 = nbh*128;
    int wm = (w>>1)*64, wn = (w&1)*64;
    int st = (33*spl + 3) >> 2;          // 0,9,17,25
    int en = (33*spl + 36) >> 2;         // 9,17,25,33
    const f16* Bbase = Vt + (size_t)b*1048576 + (size_t)h0*4096;
    f32x4 acc[4][4] = {};
    int currow = -1;
    for (int idx = st; idx < en; ++idx) {
      int row = (idx <= p) ? p : 31-p;
      int tb  = (idx <= p) ? idx : idx - (p+1);
      if (row != currow) {
        if (currow >= 0) {
          float* E = estp + (size_t)spl*2097152 + ((size_t)(b*S_LEN) + currow*128)*256;
#pragma unroll
          for (int i=0;i<4;i++)
#pragma unroll
            for (int j2=0;j2<4;j2++)
#pragma unroll
              for (int rg=0;rg<4;rg++) {
                E[(size_t)(wm + i*16 + rr + rg)*256 + h0 + wn + j2*16 + cc] = acc[i][j2][rg];
                acc[i][j2][rg] = 0.f;
              }
        }
        currow = row;
      }
      const f16* Abase = Pws + ((size_t)(b*S_LEN) + row*128)*S_LEN;
      for (int kk=0;kk<4;kk++) {
        int t0 = tb*128 + kk*32;
        stage16<128>(Asm, Abase + t0, S_LEN, tid);
        stage16<128>(Bsm, Bbase + t0, 4096, tid);
        __syncthreads();
        mfma_step<4,4>(Asm, Bsm, lane, wm, wn, acc);
        __syncthreads();
      }
    }
    {
      float* E = estp + (size_t)spl*2097152 + ((size_t)(b*S_LEN) + currow*128)*256;
#pragma unroll
      for (int i=0;i<4;i++)
#pragma unroll
        for (int j2=0;j2<4;j2++)
#pragma unroll
          for (int rg=0;rg<4;rg++)
            E[(size_t)(wm + i*16 + rr + rg)*256 + h0 + wn + j2*16 + cc] = acc[i][j2][rg];
    }
  } else {
    // norm: 32 rows/block — lsum from rsum, then normalized attn row (+zeros)
    float* part = (float*)smem;          // 256
    float* lss  = (float*)(smem + 1024); // 32
    int nb2 = bid - 256;
    {
      int r2 = tid >> 3, j8 = tid & 7;
      int rowg = nb2*32 + r2;
      int b = rowg >> 12, srow = rowg & 4095;
      int sb = srow >> 7, rowin = srow & 127;
      const float* R = rsum + ((size_t)((b*32+sb)*32))*256 + rowin;
      float s = 0.f;
      for (int tb = j8; tb <= sb; tb += 8) s += R[tb*256] + R[tb*256+128];
      part[tid] = s;
    }
    __syncthreads();
    if (tid < 32) {
      float s = 0.f;
#pragma unroll
      for (int u=0;u<8;u++) s += part[tid*8+u];
      lss[tid] = s;
      lsum[nb2*32 + tid] = s;
    }
    __syncthreads();
    for (int r2 = 0; r2 < 32; ++r2) {
      int rowg = nb2*32 + r2;
      int srow = rowg & 4095;
      float invl = 1.0f / lss[r2];
      const f16* src = Pws + (size_t)rowg*S_LEN;
      float4* dst = (float4*)(attn + (size_t)rowg*S_LEN);
      for (int q = tid; q < 1024; q += 256) {
        int t0 = q*4;
        float4 o = make_float4(0.f,0.f,0.f,0.f);
        if (t0 <= srow) {
          f16x4 pv4 = *(const f16x4*)(src + t0);
          o.x = (float)pv4[0]*invl;
          o.y = (t0+1 <= srow) ? (float)pv4[1]*invl : 0.f;
          o.z = (t0+2 <= srow) ? (float)pv4[2]*invl : 0.f;
          o.w = (t0+3 <= srow) ? (float)pv4[3]*invl : 0.f;
        }
        dst[q] = o;
      }
    }
  }
  gbar(bar);

  // ---------------- phase 3: output projection (512 jobs) ----------------
  {
    f16* Asm = (f16*)smem;                          // 16x32
    f16* Bsm = (f16*)(smem + 1024);                 // 256x32
    float* bias_s = (float*)(smem + 1024 + 16384);  // 256
    float* ls = (float*)(smem + 1024 + 16384 + 1024); // 16
    int m0 = bid*16;
    int b = m0 >> 12, s0 = m0 & 4095;
    bias_s[tid] = bias[3*256 + tid];
    if (tid < 16) ls[tid] = 1.0f / lsum[b*S_LEN + s0 + tid];
    __syncthreads();
    int wn = w*64;
    const f16* Bt = Mt + 3*65536;
    f32x4 acc[1][4] = {};
    for (int kb=0;kb<8;kb++) {
      if (tid < 128) {   // A: 16x32, sum the 4 dense split-K partials
        int row = tid >> 3, c4 = tid & 7;
        const float* basep = estp + ((size_t)(b*S_LEN) + s0 + row)*256 + kb*32 + c4*4;
        float4 v = make_float4(0.f,0.f,0.f,0.f);
#pragma unroll
        for (int ch = 0; ch < 4; ++ch) {
          float4 q = *(const float4*)(basep + (size_t)ch*2097152);
          v.x += q.x; v.y += q.y; v.z += q.z; v.w += q.w;
        }
        float scl = ls[row];
        f16x4 h; h[0]=(f16)(v.x*scl); h[1]=(f16)(v.y*scl); h[2]=(f16)(v.z*scl); h[3]=(f16)(v.w*scl);
        int slot = (((c4 >> 1) ^ ((row >> 1) & 3)) << 3) + (c4 & 1)*4;
        *(f16x4*)(Asm + row*32 + slot) = h;
      }
      stage16<256>(Bsm, Bt + kb*32, 256, tid);
      __syncthreads();
      mfma_step<1,4>(Asm, Bsm, lane, 0, wn, acc);
      __syncthreads();
    }
#pragma unroll
    for (int j=0;j<4;j++) {
      int cg = wn + j*16 + cc;
      int comp = cg >> 7, h = cg & 127;
      float bv = bias_s[cg];
#pragma unroll
      for (int rg=0;rg<4;rg++) {
        int s = s0 + rr + rg;
        outp[(((size_t)(b*2 + comp))*S_LEN + s)*128 + h] = acc[0][j][rg] + bv;
      }
    }
  }
}

extern "C" void kernel_launch(void* const* d_in, const int* in_sizes, int n_in,
                              void* d_out, int out_size, void* d_ws, size_t ws_size,
                              hipStream_t stream) {
  (void)in_sizes; (void)n_in; (void)out_size;
  if (ws_size < (size_t)WS_NEED) return;  // fail loudly (output stays poisoned)
  char* ws = (char*)d_ws;
  f16*   Mt   = (f16*)(ws + MT_OFF);
  float* bias = (float*)(ws + BIAS_OFF);
  float* sc   = (float*)(ws + SC_OFF);
  int*   bar  = (int*)(ws + BAR_OFF);
  f16*   Qh   = (f16*)(ws + QH_OFF);
  f16*   Kh   = (f16*)(ws + KH_OFF);
  f16*   Vt   = (f16*)(ws + VT_OFF);
  float* q2p  = (float*)(ws + Q2P_OFF);
  float* k2p  = (float*)(ws + K2P_OFF);
  float* lsum = (float*)(ws + LS_OFF);
  float* rsum = (float*)(ws + RS_OFF);
  float* estp = (float*)(ws + ESTP_OFF);
  f16*   Pws  = (f16*)(ws + PW_OFF);
  float* outp = (float*)d_out;
  float* attn = outp + OUT_ELEMS;

  k_init<<<2048, 256, 0, stream>>>(
      (const float*)d_in[3],  (const float*)d_in[4],  (const float*)d_in[5],  (const float*)d_in[6],
      (const float*)d_in[7],  (const float*)d_in[8],  (const float*)d_in[9],  (const float*)d_in[10],
      (const float*)d_in[11], (const float*)d_in[12], (const float*)d_in[13], (const float*)d_in[14],
      (const float*)d_in[15], (const float*)d_in[16], (const float*)d_in[17], (const float*)d_in[18],
      Mt, bias, sc, estp, bar, (const float*)d_in[19], (const float*)d_in[20]);
  k_mega<<<NBLK, 256, 0, stream>>>(
      (const float*)d_in[0], (const float*)d_in[1], (const float*)d_in[2],
      Mt, bias, sc, Qh, Kh, Vt, q2p, k2p, rsum, lsum, estp, Pws, attn, outp, bar);
}